// Round 14
// baseline (798.055 us; speedup 1.0000x reference)
//
#include <hip/hip_runtime.h>
#include <cstdint>
#include <cstddef>

#define NN 30000
#define NE 60000
#define NG 1200
#define HID 384
#define EMB 768
#define OUTD 768
#define NEGS 0.01f

typedef _Float16 f16;
typedef _Float16 f16x8 __attribute__((ext_vector_type(8)));
typedef float f32x16 __attribute__((ext_vector_type(16)));

static __device__ __forceinline__ float leaky(float x){ return x > 0.f ? x : NEGS * x; }
static __device__ __forceinline__ float elu1(float x){ return x > 0.f ? x : (expf(x) - 1.f); }
static __device__ __forceinline__ float sigm(float x){ return 1.f / (1.f + expf(-x)); }

// ---- fragment-packed (PF) layout for K=384 operands of mfma_32x32x16 ----
static __device__ __forceinline__ size_t pf_idx(int row, int col){
  return (((((size_t)(row >> 5)) * 24 + (col >> 4)) * 2 + ((col >> 3) & 1)) * 32
          + (row & 31)) * 8 + (col & 7);
}
#define PF_RB_STRIDE 12288   // 24 ks * 64 lanes * 8 elems
#define PF_KS_STRIDE 512     // 64 lanes * 8 elems
#define PF_GATE_STRIDE 147456  // 12 rb * PF_RB_STRIDE  (= HID*HID)

// ---------------- f32 tiled GEMM (tables only) ----------------
__global__ __launch_bounds__(256) void k_gemm(
    const float* __restrict__ A, const float* __restrict__ B,
    const float* __restrict__ bias, float* __restrict__ C,
    int M, int N, int K, int act)
{
  __shared__ float As[16][65];
  __shared__ float Bs[16][65];
  const int tid = threadIdx.x;
  const int tx = tid & 15, ty = tid >> 4;
  const int row0 = blockIdx.y * 64, col0 = blockIdx.x * 64;
  const int ar = tid >> 2, ak = (tid & 3) << 2;
  const int bk = tid >> 4, bc = (tid & 15) << 2;
  float acc[4][4] = {};
  for (int k0 = 0; k0 < K; k0 += 16) {
    float4 av = make_float4(0.f, 0.f, 0.f, 0.f);
    if (row0 + ar < M)
      av = *(const float4*)(A + (size_t)(row0 + ar) * K + k0 + ak);
    As[ak + 0][ar] = av.x; As[ak + 1][ar] = av.y;
    As[ak + 2][ar] = av.z; As[ak + 3][ar] = av.w;
    float4 bv = *(const float4*)(B + (size_t)(k0 + bk) * N + col0 + bc);
    Bs[bk][bc + 0] = bv.x; Bs[bk][bc + 1] = bv.y;
    Bs[bk][bc + 2] = bv.z; Bs[bk][bc + 3] = bv.w;
    __syncthreads();
#pragma unroll
    for (int kk = 0; kk < 16; kk++) {
      float a[4], b[4];
#pragma unroll
      for (int i = 0; i < 4; i++) a[i] = As[kk][(ty << 2) + i];
#pragma unroll
      for (int j = 0; j < 4; j++) b[j] = Bs[kk][(tx << 2) + j];
#pragma unroll
      for (int i = 0; i < 4; i++)
#pragma unroll
        for (int j = 0; j < 4; j++)
          acc[i][j] = fmaf(a[i], b[j], acc[i][j]);
    }
    __syncthreads();
  }
#pragma unroll
  for (int i = 0; i < 4; i++) {
    int r = row0 + (ty << 2) + i;
    if (r >= M) continue;
#pragma unroll
    for (int j = 0; j < 4; j++) {
      int c = col0 + (tx << 2) + j;
      float v = acc[i][j];
      if (bias) v += bias[c];
      if (act == 1) v = leaky(v);
      else if (act == 2) v = elu1(v);
      else if (act == 3) v = fmaxf(v, 0.f);
      C[(size_t)r * N + c] = v;
    }
  }
}

// ------------- MFMA f16 GEMM, clean variant -------------
__global__ __launch_bounds__(256) void k_hgemm(
    const f16* __restrict__ Apf, const f16* __restrict__ Bpf,
    const float* __restrict__ bias, float* __restrict__ Cf, f16* __restrict__ Ch,
    int M, int Nn, int act)
{
  const int nct = Nn >> 7;
  const int id = blockIdx.x;
  const int lane8 = id & 7, chunk = id >> 3;
  const int ct = chunk % nct, rg = chunk / nct;
  const int rt = rg * 8 + lane8;
  const int Mt = (M + 127) >> 7;
  if (rt >= Mt) return;
  const int r0 = rt * 128, n0 = ct * 128;
  const int tid = threadIdx.x;
  const int wid = tid >> 6, lane = tid & 63;
  const int wr = wid >> 1, wc = wid & 1;
  const int l31 = lane & 31, lhi = lane >> 5;
  const size_t lane_off = (size_t)(lhi * 32 + l31) * 8;
  const f16* pA[2]; const f16* pB[2];
#pragma unroll
  for (int i = 0; i < 2; i++) {
    pA[i] = Apf + (size_t)(r0 / 32 + wr * 2 + i) * PF_RB_STRIDE + lane_off;
    pB[i] = Bpf + (size_t)(n0 / 32 + wc * 2 + i) * PF_RB_STRIDE + lane_off;
  }
  f32x16 acc[2][2];
#pragma unroll
  for (int i = 0; i < 2; i++)
#pragma unroll
    for (int j = 0; j < 2; j++)
#pragma unroll
      for (int r = 0; r < 16; r++) acc[i][j][r] = 0.f;
  f16x8 af[2], bf[2], naf[2], nbf[2];
#pragma unroll
  for (int i = 0; i < 2; i++) { af[i] = *(const f16x8*)(pA[i]); bf[i] = *(const f16x8*)(pB[i]); }
#pragma unroll 4
  for (int ks = 0; ks < 24; ks++) {
    const size_t noff = (size_t)(ks < 23 ? ks + 1 : 23) * PF_KS_STRIDE;
#pragma unroll
    for (int i = 0; i < 2; i++) { naf[i] = *(const f16x8*)(pA[i] + noff); nbf[i] = *(const f16x8*)(pB[i] + noff); }
#pragma unroll
    for (int i = 0; i < 2; i++)
#pragma unroll
      for (int j = 0; j < 2; j++)
        acc[i][j] = __builtin_amdgcn_mfma_f32_32x32x16_f16(af[i], bf[j], acc[i][j], 0, 0, 0);
#pragma unroll
    for (int i = 0; i < 2; i++) { af[i] = naf[i]; bf[i] = nbf[i]; }
  }
#pragma unroll
  for (int i = 0; i < 2; i++)
#pragma unroll
    for (int j = 0; j < 2; j++) {
      int col = n0 + wc * 64 + j * 32 + l31;
      float bv = bias ? bias[col] : 0.f;
#pragma unroll
      for (int r = 0; r < 16; r++) {
        int row = r0 + wr * 64 + i * 32 + (r & 3) + 8 * (r >> 2) + 4 * lhi;
        if (row < M) {
          float v = acc[i][j][r] + bv;
          if (act == 1) v = leaky(v);
          else if (act == 2) v = elu1(v);
          else if (act == 3) v = fmaxf(v, 0.f);
          if (Cf) Cf[(size_t)row * Nn + col] = v;
          if (Ch) Ch[pf_idx(row, col)] = (f16)v;  // only used when Nn==HID
        }
      }
    }
}

// ------------- MFMA f16 GEMM + fused row-dot epilogue (separate instantiation) -------------
__global__ __launch_bounds__(256) void k_hgemm_dot(
    const f16* __restrict__ Apf, const f16* __restrict__ Bpf,
    float* __restrict__ Cf, f16* __restrict__ Ch, int M,
    const float* __restrict__ dv1, const float* __restrict__ dv2,
    float* __restrict__ od1, float* __restrict__ od2)
{
  const int nct = HID >> 7;  // 3
  const int id = blockIdx.x;
  const int lane8 = id & 7, chunk = id >> 3;
  const int ct = chunk % nct, rg = chunk / nct;
  const int rt = rg * 8 + lane8;
  const int Mt = (M + 127) >> 7;
  if (rt >= Mt) return;
  const int r0 = rt * 128, n0 = ct * 128;
  const int tid = threadIdx.x;
  const int wid = tid >> 6, lane = tid & 63;
  const int wr = wid >> 1, wc = wid & 1;
  const int l31 = lane & 31, lhi = lane >> 5;
  const size_t lane_off = (size_t)(lhi * 32 + l31) * 8;
  const f16* pA[2]; const f16* pB[2];
#pragma unroll
  for (int i = 0; i < 2; i++) {
    pA[i] = Apf + (size_t)(r0 / 32 + wr * 2 + i) * PF_RB_STRIDE + lane_off;
    pB[i] = Bpf + (size_t)(n0 / 32 + wc * 2 + i) * PF_RB_STRIDE + lane_off;
  }
  f32x16 acc[2][2];
#pragma unroll
  for (int i = 0; i < 2; i++)
#pragma unroll
    for (int j = 0; j < 2; j++)
#pragma unroll
      for (int r = 0; r < 16; r++) acc[i][j][r] = 0.f;
  f16x8 af[2], bf[2], naf[2], nbf[2];
#pragma unroll
  for (int i = 0; i < 2; i++) { af[i] = *(const f16x8*)(pA[i]); bf[i] = *(const f16x8*)(pB[i]); }
#pragma unroll 4
  for (int ks = 0; ks < 24; ks++) {
    const size_t noff = (size_t)(ks < 23 ? ks + 1 : 23) * PF_KS_STRIDE;
#pragma unroll
    for (int i = 0; i < 2; i++) { naf[i] = *(const f16x8*)(pA[i] + noff); nbf[i] = *(const f16x8*)(pB[i] + noff); }
#pragma unroll
    for (int i = 0; i < 2; i++)
#pragma unroll
      for (int j = 0; j < 2; j++)
        acc[i][j] = __builtin_amdgcn_mfma_f32_32x32x16_f16(af[i], bf[j], acc[i][j], 0, 0, 0);
#pragma unroll
    for (int i = 0; i < 2; i++) { af[i] = naf[i]; bf[i] = nbf[i]; }
  }
#pragma unroll
  for (int i = 0; i < 2; i++)
#pragma unroll
    for (int j = 0; j < 2; j++) {
      int col = n0 + wc * 64 + j * 32 + l31;
#pragma unroll
      for (int r = 0; r < 16; r++) {
        int row = r0 + wr * 64 + i * 32 + (r & 3) + 8 * (r >> 2) + 4 * lhi;
        if (row < M) {
          float v = acc[i][j][r];
          Cf[(size_t)row * HID + col] = v;
          if (Ch) Ch[pf_idx(row, col)] = (f16)v;
        }
      }
    }
  // fused row-dot epilogue on raw accumulators
  const float w1a = dv1[n0 + wc * 64 + l31];
  const float w1b = dv1[n0 + wc * 64 + 32 + l31];
  const float w2a = dv2 ? dv2[n0 + wc * 64 + l31] : 0.f;
  const float w2b = dv2 ? dv2[n0 + wc * 64 + 32 + l31] : 0.f;
#pragma unroll
  for (int i = 0; i < 2; i++)
#pragma unroll
    for (int r = 0; r < 16; r++) {
      int row = r0 + wr * 64 + i * 32 + (r & 3) + 8 * (r >> 2) + 4 * lhi;
      float p1 = acc[i][0][r] * w1a + acc[i][1][r] * w1b;
      float p2 = acc[i][0][r] * w2a + acc[i][1][r] * w2b;
#pragma unroll
      for (int o = 16; o; o >>= 1) {
        p1 += __shfl_xor(p1, o, 64);
        p2 += __shfl_xor(p2, o, 64);
      }
      if (l31 == 0 && row < M) {
        atomicAdd(&od1[row], p1);
        if (od2) atomicAdd(&od2[row], p2);
      }
    }
}

// ------------- MFMA f16 fused GRU v6: 4 accs, 2-deep pipeline on ALL operands -------------
// 2-slot software pipeline; ks&1 under unroll-4 keeps indices compile-time (no scratch).
__global__ __launch_bounds__(256) void k_gru_hgemm(
    const f16* __restrict__ Upf, const f16* __restrict__ Hpf,
    const f16* __restrict__ Wip, const f16* __restrict__ Whp,
    const float* __restrict__ bi, const float* __restrict__ bh,
    float* __restrict__ Xo, f16* __restrict__ Xoh, int M)
{
  const int id = blockIdx.x;
  const int lane8 = id & 7, chunk = id >> 3;
  const int ct = chunk % 6, rg = chunk / 6;
  const int rt = rg * 8 + lane8;
  const int Mt = (M + 63) >> 6;
  if (rt >= Mt) return;
  const int r0 = rt * 64, c0 = ct * 64;
  const int tid = threadIdx.x;
  const int wid = tid >> 6, lane = tid & 63;
  const int wr = wid >> 1, wc = wid & 1;
  const int l31 = lane & 31, lhi = lane >> 5;
  const size_t lane_off = (size_t)(lhi * 32 + l31) * 8;
  const f16* pU  = Upf + (size_t)(r0 / 32 + wr) * PF_RB_STRIDE + lane_off;
  const f16* pH  = Hpf + (size_t)(r0 / 32 + wr) * PF_RB_STRIDE + lane_off;
  const f16* pWi = Wip + (size_t)(c0 / 32 + wc) * PF_RB_STRIDE + lane_off;
  const f16* pWh = Whp + (size_t)(c0 / 32 + wc) * PF_RB_STRIDE + lane_off;
#define Z16 {0,0,0,0,0,0,0,0,0,0,0,0,0,0,0,0}
  f32x16 accR = Z16, accZ = Z16, aN = Z16, hN = Z16;
  f16x8 au[2], ah[2], bir[2], biz[2], bin[2], bhr[2], bhz[2], bhn[2];
#pragma unroll
  for (int s = 0; s < 2; s++) {
    const size_t off = (size_t)s * PF_KS_STRIDE;
    au[s]  = *(const f16x8*)(pU + off);
    ah[s]  = *(const f16x8*)(pH + off);
    bir[s] = *(const f16x8*)(pWi + off);
    biz[s] = *(const f16x8*)(pWi + PF_GATE_STRIDE + off);
    bin[s] = *(const f16x8*)(pWi + 2 * PF_GATE_STRIDE + off);
    bhr[s] = *(const f16x8*)(pWh + off);
    bhz[s] = *(const f16x8*)(pWh + PF_GATE_STRIDE + off);
    bhn[s] = *(const f16x8*)(pWh + 2 * PF_GATE_STRIDE + off);
  }
#pragma unroll 4
  for (int ks = 0; ks < 24; ks++) {
    const int cur = ks & 1;
    const size_t noff = (size_t)(ks < 22 ? ks + 2 : 23) * PF_KS_STRIDE;
    accR = __builtin_amdgcn_mfma_f32_32x32x16_f16(au[cur], bir[cur], accR, 0, 0, 0);
    accR = __builtin_amdgcn_mfma_f32_32x32x16_f16(ah[cur], bhr[cur], accR, 0, 0, 0);
    accZ = __builtin_amdgcn_mfma_f32_32x32x16_f16(au[cur], biz[cur], accZ, 0, 0, 0);
    accZ = __builtin_amdgcn_mfma_f32_32x32x16_f16(ah[cur], bhz[cur], accZ, 0, 0, 0);
    aN   = __builtin_amdgcn_mfma_f32_32x32x16_f16(au[cur], bin[cur], aN, 0, 0, 0);
    hN   = __builtin_amdgcn_mfma_f32_32x32x16_f16(ah[cur], bhn[cur], hN, 0, 0, 0);
    au[cur]  = *(const f16x8*)(pU + noff);
    ah[cur]  = *(const f16x8*)(pH + noff);
    bir[cur] = *(const f16x8*)(pWi + noff);
    biz[cur] = *(const f16x8*)(pWi + PF_GATE_STRIDE + noff);
    bin[cur] = *(const f16x8*)(pWi + 2 * PF_GATE_STRIDE + noff);
    bhr[cur] = *(const f16x8*)(pWh + noff);
    bhz[cur] = *(const f16x8*)(pWh + PF_GATE_STRIDE + noff);
    bhn[cur] = *(const f16x8*)(pWh + 2 * PF_GATE_STRIDE + noff);
  }
  const int col = c0 + wc * 32 + l31;  // in [0, 384)
  const float brz = bi[col] + bh[col];
  const float bzz = bi[HID + col] + bh[HID + col];
  const float bin_ = bi[2 * HID + col];
  const float bhn_ = bh[2 * HID + col];
#pragma unroll
  for (int r = 0; r < 16; r++) {
    int row = r0 + wr * 32 + (r & 3) + 8 * (r >> 2) + 4 * lhi;
    if (row < M) {
      float rg_ = sigm(accR[r] + brz);
      float zg  = sigm(accZ[r] + bzz);
      float ng  = tanhf(aN[r] + bin_ + rg_ * (hN[r] + bhn_));
      float hp  = (float)Hpf[pf_idx(row, col)];
      float o = (1.f - zg) * ng + zg * hp;
      o = fmaxf(o, 0.f);
      if (Xo) Xo[(size_t)row * HID + col] = o;
      Xoh[pf_idx(row, col)] = (f16)o;
    }
  }
}

// ---- single fused weight pack: all 11 weights -> PF f16 in one launch ----
__global__ void k_wpack_all(
    const float* __restrict__ w0, const float* __restrict__ w1,
    const float* __restrict__ w2, const float* __restrict__ w3,
    const float* __restrict__ w4, const float* __restrict__ w5,
    const float* __restrict__ w6, const float* __restrict__ w7,
    const float* __restrict__ w8, const float* __restrict__ w9,
    const float* __restrict__ w10,
    f16* __restrict__ d0, f16* __restrict__ d1, f16* __restrict__ d2,
    f16* __restrict__ d3, f16* __restrict__ d4, f16* __restrict__ d5,
    f16* __restrict__ d6, f16* __restrict__ d7, f16* __restrict__ d8,
    f16* __restrict__ d9, f16* __restrict__ d10)
{
  long t = (long)blockIdx.x * blockDim.x + threadIdx.x;
  if (t >= 3538944L) return;
  const float* W; f16* Wp; int Nn; long tt;
  if (t < 589824L) {
    int s = (int)(t / 147456L); tt = t - (long)s * 147456L; Nn = HID;
    if (s == 0) { W = w0; Wp = d0; } else if (s == 1) { W = w1; Wp = d1; }
    else if (s == 2) { W = w2; Wp = d2; } else { W = w3; Wp = d3; }
  } else if (t < 3244032L) {
    long u = t - 589824L;
    int s = (int)(u / 442368L); tt = u - (long)s * 442368L; Nn = 3 * HID;
    if (s == 0) { W = w4; Wp = d4; } else if (s == 1) { W = w5; Wp = d5; }
    else if (s == 2) { W = w6; Wp = d6; } else if (s == 3) { W = w7; Wp = d7; }
    else if (s == 4) { W = w8; Wp = d8; } else { W = w9; Wp = d9; }
  } else {
    tt = t - 3244032L; Nn = OUTD; W = w10; Wp = d10;
  }
  int elem = (int)(tt & 7); long c = tt >> 3;
  int l31 = (int)(c & 31); long q = c >> 5;
  int lhi = (int)(q & 1); long p = q >> 1;
  int ks = (int)(p % 24); int rb = (int)(p / 24);
  int n = rb * 32 + l31, k = ks * 16 + lhi * 8 + elem;
  Wp[tt] = (f16)W[(size_t)k * Nn + n];
}

// node embed v2: one wave per row. Writes PF f16 only; fuses xr = x1 @ att_r.
__global__ void k_node_embed2(const int* __restrict__ xi, const float* __restrict__ T1,
                              const float* __restrict__ b, const float* __restrict__ att_r,
                              f16* __restrict__ x1h, float* __restrict__ xr, int n)
{
  int w = (int)(((long)blockIdx.x * blockDim.x + threadIdx.x) >> 6);
  int lane = threadIdx.x & 63;
  if (w >= n) return;
  int idx[9];
#pragma unroll
  for (int j = 0; j < 9; j++) idx[j] = xi[w * 9 + j];
  float s = 0.f;
#pragma unroll
  for (int t = 0; t < 6; t++) {
    int c = lane + 64 * t;
    float v = b[c];
#pragma unroll
    for (int j = 0; j < 9; j++) v += T1[(size_t)idx[j] * HID + c];
    v = leaky(v);
    x1h[pf_idx(w, c)] = (f16)v;
    s += v * att_r[c];
  }
  for (int o = 32; o; o >>= 1) s += __shfl_down(s, o, 64);
  if (lane == 0) xr[w] = s;
}

// one 64-lane wave per row: out[r] = dot(X[r,:], v)
__global__ void k_rowdot(const float* __restrict__ X, const float* __restrict__ v,
                         float* __restrict__ out, int M)
{
  int w = (int)(((long)blockIdx.x * blockDim.x + threadIdx.x) >> 6);
  int lane = threadIdx.x & 63;
  if (w >= M) return;
  float s = 0.f;
  for (int j = lane; j < HID; j += 64) s += X[(size_t)w * HID + j] * v[j];
  for (int o = 32; o; o >>= 1) s += __shfl_down(s, o, 64);
  if (lane == 0) out[w] = s;
}

// fused init: cnt=0, sS/sD/a_node=0, gstart via binary search (batch sorted)
__global__ void k_init(const int* __restrict__ batch, int* __restrict__ cnt,
                       float* __restrict__ sz, int* __restrict__ gstart, int n, int G)
{
  int i = (int)((long)blockIdx.x * blockDim.x + threadIdx.x);
  if (i < n) {
    cnt[i] = 0;
    sz[i] = 0.f; sz[n + i] = 0.f; sz[2 * n + i] = 0.f;  // sS, sD, a_node
  }
  if (i <= G) {
    int lo = 0, hi = n;
    while (lo < hi) { int mid = (lo + hi) >> 1; if (batch[mid] < i) lo = mid + 1; else hi = mid; }
    gstart[i] = lo;
  }
}

// ---- CSR build over dst: degree count -> single-block scan -> fill ----
__global__ void k_deg(const int* __restrict__ dst, int* __restrict__ cnt, int ne)
{
  int e = (int)((long)blockIdx.x * blockDim.x + threadIdx.x);
  if (e >= ne) return;
  atomicAdd(&cnt[dst[e]], 1);
}

__global__ __launch_bounds__(1024) void k_scan(const int* __restrict__ cnt,
                                               int* __restrict__ rowptr,
                                               int* __restrict__ cursor)
{
  __shared__ int part[1024];
  const int tid = threadIdx.x;
  const int c0 = tid * 30, c1 = min(c0 + 30, NN);
  int s = 0;
  for (int i = c0; i < c1; i++) s += cnt[i];
  part[tid] = s;
  __syncthreads();
  for (int o = 1; o < 1024; o <<= 1) {
    int v = (tid >= o) ? part[tid - o] : 0;
    __syncthreads();
    part[tid] += v;
    __syncthreads();
  }
  int run = (tid ? part[tid - 1] : 0);
  for (int i = c0; i < c1; i++) { rowptr[i] = run; cursor[i] = run; run += cnt[i]; }
  if (tid == 1023) rowptr[NN] = part[1023];
}

__global__ void k_fill(const int* __restrict__ dst, int* __restrict__ cursor,
                       int* __restrict__ elist, int ne)
{
  int e = (int)((long)blockIdx.x * blockDim.x + threadIdx.x);
  if (e >= ne) return;
  int p = atomicAdd(&cursor[dst[e]], 1);
  elist[p] = e;
}

// ---- GATEConv fused aggregation: one wave per node, online softmax, PF out ----
__global__ void k_gate_agg(const float* __restrict__ P, const float* __restrict__ Te,
                           const int* __restrict__ ei, const int* __restrict__ eai,
                           const float* __restrict__ attl, const float* __restrict__ xr,
                           const int* __restrict__ rowptr, const int* __restrict__ elist,
                           f16* __restrict__ Hout, int n)
{
  int node = (int)(((long)blockIdx.x * blockDim.x + threadIdx.x) >> 6);
  int lane = threadIdx.x & 63;
  if (node >= n) return;
  const int e0 = rowptr[node], e1 = rowptr[node + 1];
  const float xrd = xr[node];
  float h0 = 0.f, h1 = 0.f, h2 = 0.f, h3 = 0.f, h4 = 0.f, h5 = 0.f;
  float mx = -3.4e38f, s = 0.f;
  for (int q = e0; q < e1; q++) {
    int e = elist[q];
    int src = ei[e];
    int i0 = eai[e * 3], i1 = eai[e * 3 + 1], i2 = eai[e * 3 + 2];
    float m[6];
    float dot = 0.f;
#pragma unroll
    for (int t = 0; t < 6; t++) {
      int c = lane + 64 * t;
      float v = P[(size_t)src * HID + c] + Te[(size_t)i0 * HID + c]
              + Te[(size_t)i1 * HID + c] + Te[(size_t)i2 * HID + c];
      v = leaky(v);
      m[t] = v;
      dot += v * attl[c];
    }
#pragma unroll
    for (int o = 32; o; o >>= 1) dot += __shfl_xor(dot, o, 64);
    float a = leaky(dot + xrd);
    if (a > mx) {
      float f = expf(mx - a);   // first edge: exp(-huge)=0
      s *= f; h0 *= f; h1 *= f; h2 *= f; h3 *= f; h4 *= f; h5 *= f;
      mx = a;
    }
    float w = expf(a - mx);
    s += w;
    h0 += w * m[0]; h1 += w * m[1]; h2 += w * m[2];
    h3 += w * m[3]; h4 += w * m[4]; h5 += w * m[5];
  }
  const float inv = 1.f / (s + 1e-16f);
  Hout[pf_idx(node, lane)]           = (f16)(h0 * inv);
  Hout[pf_idx(node, lane + 64)]      = (f16)(h1 * inv);
  Hout[pf_idx(node, lane + 128)]     = (f16)(h2 * inv);
  Hout[pf_idx(node, lane + 192)]     = (f16)(h3 * inv);
  Hout[pf_idx(node, lane + 256)]     = (f16)(h4 * inv);
  Hout[pf_idx(node, lane + 320)]     = (f16)(h5 * inv);
}

// ---- GAT fused aggregation: one wave per node, online softmax, +bias +elu, PF out ----
__global__ void k_gat_agg(const float* __restrict__ XL, const int* __restrict__ ei,
                          const float* __restrict__ sS, const float* __restrict__ sD,
                          const float* __restrict__ gat_b,
                          const int* __restrict__ rowptr, const int* __restrict__ elist,
                          f16* __restrict__ Hout, int n)
{
  int node = (int)(((long)blockIdx.x * blockDim.x + threadIdx.x) >> 6);
  int lane = threadIdx.x & 63;
  if (node >= n) return;
  const int e0 = rowptr[node], e1 = rowptr[node + 1];
  const float sDn = sD[node];
  float h0 = 0.f, h1 = 0.f, h2 = 0.f, h3 = 0.f, h4 = 0.f, h5 = 0.f;
  float mx = -3.4e38f, s = 0.f;
  for (int q = e0; q < e1; q++) {
    int e = elist[q];
    int src = ei[e];
    float a = leaky(sS[src] + sDn);
    if (a > mx) {
      float f = expf(mx - a);
      s *= f; h0 *= f; h1 *= f; h2 *= f; h3 *= f; h4 *= f; h5 *= f;
      mx = a;
    }
    float w = expf(a - mx);
    s += w;
    const float* row = XL + (size_t)src * HID;
    h0 += w * row[lane];
    h1 += w * row[lane + 64];
    h2 += w * row[lane + 128];
    h3 += w * row[lane + 192];
    h4 += w * row[lane + 256];
    h5 += w * row[lane + 320];
  }
  const float inv = 1.f / (s + 1e-16f);
  Hout[pf_idx(node, lane)]       = (f16)elu1(h0 * inv + gat_b[lane]);
  Hout[pf_idx(node, lane + 64)]  = (f16)elu1(h1 * inv + gat_b[lane + 64]);
  Hout[pf_idx(node, lane + 128)] = (f16)elu1(h2 * inv + gat_b[lane + 128]);
  Hout[pf_idx(node, lane + 192)] = (f16)elu1(h3 * inv + gat_b[lane + 192]);
  Hout[pf_idx(node, lane + 256)] = (f16)elu1(h4 * inv + gat_b[lane + 256]);
  Hout[pf_idx(node, lane + 320)] = (f16)elu1(h5 * inv + gat_b[lane + 320]);
}

// per-graph sum (sorted batch): OUTa = relu(sum x3), dual f32 + PF
__global__ __launch_bounds__(384) void k_graph_sum(const float* __restrict__ X,
                                                   const int* __restrict__ gstart,
                                                   float* __restrict__ OUTa,
                                                   f16* __restrict__ OUTaPF)
{
  const int g = blockIdx.x;
  const int tid = threadIdx.x;
  const int s0 = gstart[g], s1 = gstart[g + 1];
  float acc = 0.f;
  for (int i = s0; i < s1; i++) acc += X[(size_t)i * HID + tid];
  acc = fmaxf(acc, 0.f);
  OUTa[(size_t)g * HID + tid] = acc;
  OUTaPF[pf_idx(g, tid)] = (f16)acc;
}

// fused per-graph readout iteration: a_g dot + segment softmax + weighted sum + elu -> HM PF
__global__ __launch_bounds__(384) void k_mol_iter(
    const float* __restrict__ cur, const float* __restrict__ XLm,
    const float* __restrict__ a_node, const float* __restrict__ w_g,
    const float* __restrict__ mol_b, const int* __restrict__ gstart,
    f16* __restrict__ HMp)
{
  const int g = blockIdx.x;
  const int tid = threadIdx.x;
  const int lane = tid & 63, wv = tid >> 6;  // 6 waves
  __shared__ float red[6];
  __shared__ float wbuf[384];
  __shared__ float sh[3];
  const int s0 = gstart[g], s1 = gstart[g + 1];
  float p = cur[(size_t)g * HID + tid] * w_g[tid];
  for (int o = 32; o; o >>= 1) p += __shfl_down(p, o, 64);
  if (lane == 0) red[wv] = p;
  __syncthreads();
  if (tid == 0) { float s = 0.f; for (int i = 0; i < 6; i++) s += red[i]; sh[0] = s; }
  __syncthreads();
  const float ag = sh[0];
  float mx = -3.4e38f;
  for (int n = s0 + tid; n < s1; n += 384) mx = fmaxf(mx, leaky(a_node[n] + ag));
  for (int o = 32; o; o >>= 1) mx = fmaxf(mx, __shfl_down(mx, o, 64));
  __syncthreads();
  if (lane == 0) red[wv] = mx;
  __syncthreads();
  if (tid == 0) { float m = red[0]; for (int i = 1; i < 6; i++) m = fmaxf(m, red[i]); sh[1] = m; }
  __syncthreads();
  const float gmx = sh[1];
  float sm = 0.f;
  for (int n = s0 + tid; n < s1; n += 384) sm += expf(leaky(a_node[n] + ag) - gmx);
  for (int o = 32; o; o >>= 1) sm += __shfl_down(sm, o, 64);
  __syncthreads();
  if (lane == 0) red[wv] = sm;
  __syncthreads();
  if (tid == 0) { float s = 0.f; for (int i = 0; i < 6; i++) s += red[i]; sh[2] = s; }
  __syncthreads();
  const float inv = 1.f / (sh[2] + 1e-16f);
  float h = 0.f;
  for (int base = s0; base < s1; base += 384) {
    int cnt = min(384, s1 - base);
    __syncthreads();
    if (tid < cnt) wbuf[tid] = expf(leaky(a_node[base + tid] + ag) - gmx) * inv;
    __syncthreads();
    for (int k = 0; k < cnt; k++) h += XLm[(size_t)(base + k) * HID + tid] * wbuf[k];
  }
  h = elu1(h + mol_b[tid]);
  HMp[pf_idx(g, tid)] = (f16)h;
}

extern "C" void kernel_launch(void* const* d_in, const int* in_sizes, int n_in,
                              void* d_out, int out_size, void* d_ws, size_t ws_size,
                              hipStream_t stream)
{
  const int* x_idx = (const int*)d_in[0];
  const int* edge_index = (const int*)d_in[1];
  const int* eai = (const int*)d_in[2];
  const int* batch = (const int*)d_in[3];
  const float* x_emb = (const float*)d_in[4];
  const float* e_emb = (const float*)d_in[5];
  const float* lin1_W = (const float*)d_in[6];
  const float* lin1_b = (const float*)d_in[7];
  const float* att_l = (const float*)d_in[8];
  const float* att_r = (const float*)d_in[9];
  const float* gl1_W = (const float*)d_in[10];
  const float* gl2_W = (const float*)d_in[11];
  const float* gate_b = (const float*)d_in[12];
  const float* gru1_Wi = (const float*)d_in[13];
  const float* gru1_Wh = (const float*)d_in[14];
  const float* gru1_bi = (const float*)d_in[15];
  const float* gru1_bh = (const float*)d_in[16];
  const float* gat_W = (const float*)d_in[17];
  const float* gat_as = (const float*)d_in[18];
  const float* gat_ad = (const float*)d_in[19];
  const float* gat_b = (const float*)d_in[20];
  const float* gru2_Wi = (const float*)d_in[21];
  const float* gru2_Wh = (const float*)d_in[22];
  const float* gru2_bi = (const float*)d_in[23];
  const float* gru2_bh = (const float*)d_in[24];
  const float* mol_W = (const float*)d_in[25];
  const float* mol_as = (const float*)d_in[26];
  const float* mol_ad = (const float*)d_in[27];
  const float* mol_b = (const float*)d_in[28];
  const float* mgru_Wi = (const float*)d_in[29];
  const float* mgru_Wh = (const float*)d_in[30];
  const float* mgru_bi = (const float*)d_in[31];
  const float* mgru_bh = (const float*)d_in[32];
  const float* lin2_W = (const float*)d_in[33];
  const float* lin2_b = (const float*)d_in[34];
  float* outp = (float*)d_out;

  const size_t NB = (size_t)NN * HID;
  const size_t GB = (size_t)NG * HID;
  const size_t PFH = (size_t)940 * PF_RB_STRIDE;  // f16 elems (pad rows to 30080)
  const size_t PFG = (size_t)40 * PF_RB_STRIDE;

  float* ws = (float*)d_ws;
  size_t off = 0;
  auto alloc = [&](size_t n) { float* p = ws + off; off += n; return p; };
  auto alloch = [&](size_t n) { f16* p = (f16*)(ws + off); off += (n + 1) / 2; return p; };
  float* A    = alloc(NB);
  float* B    = alloc(NB);
  f16* H1 = alloch(PFH);
  f16* H2 = alloch(PFH);
  f16* H3 = alloch(PFH);
  f16* W1p   = alloch((size_t)HID * HID);
  f16* W2p   = alloch((size_t)HID * HID);
  f16* Wgatp = alloch((size_t)HID * HID);
  f16* Wmolp = alloch((size_t)HID * HID);
  f16* Wg1ip = alloch((size_t)3 * HID * HID);
  f16* Wg1hp = alloch((size_t)3 * HID * HID);
  f16* Wg2ip = alloch((size_t)3 * HID * HID);
  f16* Wg2hp = alloch((size_t)3 * HID * HID);
  f16* Wmgip = alloch((size_t)3 * HID * HID);
  f16* Wmghp = alloch((size_t)3 * HID * HID);
  f16* Wl2p  = alloch((size_t)HID * OUTD);
  f16* OUTaPF = alloch(PFG);
  f16* OUTbPF = alloch(PFG);
  f16* HMp    = alloch(PFG);
  float* T1   = alloc((size_t)178 * HID);
  float* Te   = alloc((size_t)18 * HID);
  float* w_g  = alloc(HID);
  float* xr   = alloc(NN);
  float* sS   = alloc(NN);   // sS, sD, a_node contiguous (zeroed by k_init)
  float* sD   = alloc(NN);
  float* a_node = alloc(NN);
  float* OUTa = alloc(GB);
  float* OUTb = alloc(GB);
  int* gstart = (int*)alloc(NG + 2);
  int* cnt    = (int*)alloc(NN);
  int* rowptr = (int*)alloc(NN + 2);
  int* cursor = (int*)alloc(NN);
  int* elist  = (int*)alloc(NE);
  (void)n_in; (void)in_sizes; (void)out_size;
  if (ws_size < off * sizeof(float)) return;  // fail loud, not with a GPU fault

  const int* dstArr = edge_index + NE;
  dim3 blk(256);
  auto g1 = [](long n) { return dim3((unsigned)((n + 255) / 256)); };
  auto gw = [](long waves) { return dim3((unsigned)((waves * 64 + 255) / 256)); };
  const int MtH = (NN + 127) / 128;                       // 235
  const dim3 gH((unsigned)(8 * 3 * ((MtH + 7) / 8)));     // 720
  const int MtR = (NN + 63) / 64;                         // 469
  const dim3 gR((unsigned)(8 * 6 * ((MtR + 7) / 8)));     // 2832
  const int MtGH = (NG + 127) / 128;                      // 10
  const dim3 gF((unsigned)(8 * 6 * ((MtGH + 7) / 8)));    // 96   (Nn=OUTD)
  const int MtGR = (NG + 63) / 64;                        // 19
  const dim3 gRG((unsigned)(8 * 6 * ((MtGR + 7) / 8)));   // 144
  const float* FN = nullptr;
  float* FNm = nullptr;

  // ---- weight prep (one launch) + tables + fused init + CSR ----
  hipLaunchKernelGGL(k_wpack_all, g1(3538944L), blk, 0, stream,
                     gl1_W, gl2_W, gat_W, mol_W,
                     gru1_Wi, gru1_Wh, gru2_Wi, gru2_Wh, mgru_Wi, mgru_Wh, lin2_W,
                     W1p, W2p, Wgatp, Wmolp,
                     Wg1ip, Wg1hp, Wg2ip, Wg2hp, Wmgip, Wmghp, Wl2p);
  hipLaunchKernelGGL(k_gemm, dim3(HID / 64, 3), blk, 0, stream,
                     x_emb, lin1_W, nullptr, T1, 178, HID, EMB, 0);
  hipLaunchKernelGGL(k_gemm, dim3(HID / 64, 1), blk, 0, stream,
                     e_emb, gl1_W + (size_t)HID * HID, nullptr, Te, 18, HID, EMB, 0);
  hipLaunchKernelGGL(k_rowdot, gw(HID), blk, 0, stream, mol_W, mol_ad, w_g, HID);
  hipLaunchKernelGGL(k_init, g1(NN), blk, 0, stream, batch, cnt, sS, gstart, NN, NG);
  hipLaunchKernelGGL(k_deg, g1(NE), blk, 0, stream, dstArr, cnt, NE);
  hipLaunchKernelGGL(k_scan, dim3(1), dim3(1024), 0, stream, cnt, rowptr, cursor);
  hipLaunchKernelGGL(k_fill, g1(NE), blk, 0, stream, dstArr, cursor, elist, NE);

  // ---- x1 (PF) + fused xr ----
  hipLaunchKernelGGL(k_node_embed2, gw(NN), blk, 0, stream, x_idx, T1, lin1_b, att_r, H1, xr, NN);

  // ---- GATEConv ----
  hipLaunchKernelGGL(k_hgemm, gH, blk, 0, stream, H1, W1p, FN, B, (f16*)nullptr, NN, HID, 0); // P
  hipLaunchKernelGGL(k_gate_agg, gw(NN), blk, 0, stream, B, Te, edge_index, eai, att_l, xr,
                     rowptr, elist, H2, NN);
  hipLaunchKernelGGL(k_hgemm, gH, blk, 0, stream, H2, W2p, gate_b, (float*)nullptr, H3, NN, HID, 2); // elu(h)
  hipLaunchKernelGGL(k_gru_hgemm, gR, blk, 0, stream, H3, H1, Wg1ip, Wg1hp,
                     gru1_bi, gru1_bh, (float*)nullptr, H2, NN);            // x2 -> H2

  // ---- GAT layer ----
  hipLaunchKernelGGL(k_hgemm_dot, gH, blk, 0, stream, H2, Wgatp, B, (f16*)nullptr, NN,
                     gat_as, gat_ad, sS, sD);                               // XL + fused sS/sD
  hipLaunchKernelGGL(k_gat_agg, gw(NN), blk, 0, stream, B, edge_index, sS, sD, gat_b,
                     rowptr, elist, H1, NN);                                // elu(h2+b) -> H1
  hipLaunchKernelGGL(k_gru_hgemm, gR, blk, 0, stream, H1, H2, Wg2ip, Wg2hp,
                     gru2_bi, gru2_bh, B, H3, NN);                          // x3 -> B f32 + H3 PF

  // ---- molecule readout ----
  hipLaunchKernelGGL(k_graph_sum, dim3(NG), dim3(384), 0, stream, B, gstart, OUTa, OUTaPF);
  hipLaunchKernelGGL(k_hgemm_dot, gH, blk, 0, stream, H3, Wmolp, A, (f16*)nullptr, NN,
                     mol_as, FN, a_node, FNm);                              // XLm + fused a_node

  float* cur = OUTa;   f16* curPF = OUTaPF;
  float* nxt = OUTb;   f16* nxtPF = OUTbPF;
  for (int t = 0; t < 3; t++) {
    hipLaunchKernelGGL(k_mol_iter, dim3(NG), dim3(384), 0, stream,
                       cur, A, a_node, w_g, mol_b, gstart, HMp);
    hipLaunchKernelGGL(k_gru_hgemm, gRG, blk, 0, stream, HMp, curPF, Wmgip, Wmghp,
                       mgru_bi, mgru_bh, nxt, nxtPF, NG);
    float* tf = cur; cur = nxt; nxt = tf;
    f16* th = curPF; curPF = nxtPF; nxtPF = th;
  }

  // ---- final projection: out = cur @ lin2_W + lin2_b ----
  hipLaunchKernelGGL(k_hgemm, gF, blk, 0, stream, curPF, Wl2p, lin2_b, outp, (f16*)nullptr,
                     NG, OUTD, 0);
}

// Round 15
// 781.379 us; speedup vs baseline: 1.0213x; 1.0213x over previous
//
#include <hip/hip_runtime.h>
#include <cstdint>
#include <cstddef>

#define NN 30000
#define NE 60000
#define NG 1200
#define HID 384
#define EMB 768
#define OUTD 768
#define NEGS 0.01f

typedef _Float16 f16;
typedef _Float16 f16x8 __attribute__((ext_vector_type(8)));
typedef float f32x16 __attribute__((ext_vector_type(16)));

static __device__ __forceinline__ float leaky(float x){ return x > 0.f ? x : NEGS * x; }
static __device__ __forceinline__ float elu1(float x){ return x > 0.f ? x : (expf(x) - 1.f); }
static __device__ __forceinline__ float sigm(float x){ return 1.f / (1.f + expf(-x)); }

// ---- fragment-packed (PF) layout for K=384 operands of mfma_32x32x16 ----
static __device__ __forceinline__ size_t pf_idx(int row, int col){
  return (((((size_t)(row >> 5)) * 24 + (col >> 4)) * 2 + ((col >> 3) & 1)) * 32
          + (row & 31)) * 8 + (col & 7);
}
#define PF_RB_STRIDE 12288   // 24 ks * 64 lanes * 8 elems
#define PF_KS_STRIDE 512     // 64 lanes * 8 elems
#define PF_GATE_STRIDE 147456  // 12 rb * PF_RB_STRIDE  (= HID*HID)

// ---------------- f32 tiled GEMM (tables only) ----------------
__global__ __launch_bounds__(256) void k_gemm(
    const float* __restrict__ A, const float* __restrict__ B,
    const float* __restrict__ bias, float* __restrict__ C,
    int M, int N, int K, int act)
{
  __shared__ float As[16][65];
  __shared__ float Bs[16][65];
  const int tid = threadIdx.x;
  const int tx = tid & 15, ty = tid >> 4;
  const int row0 = blockIdx.y * 64, col0 = blockIdx.x * 64;
  const int ar = tid >> 2, ak = (tid & 3) << 2;
  const int bk = tid >> 4, bc = (tid & 15) << 2;
  float acc[4][4] = {};
  for (int k0 = 0; k0 < K; k0 += 16) {
    float4 av = make_float4(0.f, 0.f, 0.f, 0.f);
    if (row0 + ar < M)
      av = *(const float4*)(A + (size_t)(row0 + ar) * K + k0 + ak);
    As[ak + 0][ar] = av.x; As[ak + 1][ar] = av.y;
    As[ak + 2][ar] = av.z; As[ak + 3][ar] = av.w;
    float4 bv = *(const float4*)(B + (size_t)(k0 + bk) * N + col0 + bc);
    Bs[bk][bc + 0] = bv.x; Bs[bk][bc + 1] = bv.y;
    Bs[bk][bc + 2] = bv.z; Bs[bk][bc + 3] = bv.w;
    __syncthreads();
#pragma unroll
    for (int kk = 0; kk < 16; kk++) {
      float a[4], b[4];
#pragma unroll
      for (int i = 0; i < 4; i++) a[i] = As[kk][(ty << 2) + i];
#pragma unroll
      for (int j = 0; j < 4; j++) b[j] = Bs[kk][(tx << 2) + j];
#pragma unroll
      for (int i = 0; i < 4; i++)
#pragma unroll
        for (int j = 0; j < 4; j++)
          acc[i][j] = fmaf(a[i], b[j], acc[i][j]);
    }
    __syncthreads();
  }
#pragma unroll
  for (int i = 0; i < 4; i++) {
    int r = row0 + (ty << 2) + i;
    if (r >= M) continue;
#pragma unroll
    for (int j = 0; j < 4; j++) {
      int c = col0 + (tx << 2) + j;
      float v = acc[i][j];
      if (bias) v += bias[c];
      if (act == 1) v = leaky(v);
      else if (act == 2) v = elu1(v);
      else if (act == 3) v = fmaxf(v, 0.f);
      C[(size_t)r * N + c] = v;
    }
  }
}

// ------------- MFMA f16 GEMM, clean variant -------------
__global__ __launch_bounds__(256) void k_hgemm(
    const f16* __restrict__ Apf, const f16* __restrict__ Bpf,
    const float* __restrict__ bias, float* __restrict__ Cf, f16* __restrict__ Ch,
    int M, int Nn, int act)
{
  const int nct = Nn >> 7;
  const int id = blockIdx.x;
  const int lane8 = id & 7, chunk = id >> 3;
  const int ct = chunk % nct, rg = chunk / nct;
  const int rt = rg * 8 + lane8;
  const int Mt = (M + 127) >> 7;
  if (rt >= Mt) return;
  const int r0 = rt * 128, n0 = ct * 128;
  const int tid = threadIdx.x;
  const int wid = tid >> 6, lane = tid & 63;
  const int wr = wid >> 1, wc = wid & 1;
  const int l31 = lane & 31, lhi = lane >> 5;
  const size_t lane_off = (size_t)(lhi * 32 + l31) * 8;
  const f16* pA[2]; const f16* pB[2];
#pragma unroll
  for (int i = 0; i < 2; i++) {
    pA[i] = Apf + (size_t)(r0 / 32 + wr * 2 + i) * PF_RB_STRIDE + lane_off;
    pB[i] = Bpf + (size_t)(n0 / 32 + wc * 2 + i) * PF_RB_STRIDE + lane_off;
  }
  f32x16 acc[2][2];
#pragma unroll
  for (int i = 0; i < 2; i++)
#pragma unroll
    for (int j = 0; j < 2; j++)
#pragma unroll
      for (int r = 0; r < 16; r++) acc[i][j][r] = 0.f;
  f16x8 af[2], bf[2], naf[2], nbf[2];
#pragma unroll
  for (int i = 0; i < 2; i++) { af[i] = *(const f16x8*)(pA[i]); bf[i] = *(const f16x8*)(pB[i]); }
#pragma unroll 4
  for (int ks = 0; ks < 24; ks++) {
    const size_t noff = (size_t)(ks < 23 ? ks + 1 : 23) * PF_KS_STRIDE;
#pragma unroll
    for (int i = 0; i < 2; i++) { naf[i] = *(const f16x8*)(pA[i] + noff); nbf[i] = *(const f16x8*)(pB[i] + noff); }
#pragma unroll
    for (int i = 0; i < 2; i++)
#pragma unroll
      for (int j = 0; j < 2; j++)
        acc[i][j] = __builtin_amdgcn_mfma_f32_32x32x16_f16(af[i], bf[j], acc[i][j], 0, 0, 0);
#pragma unroll
    for (int i = 0; i < 2; i++) { af[i] = naf[i]; bf[i] = nbf[i]; }
  }
#pragma unroll
  for (int i = 0; i < 2; i++)
#pragma unroll
    for (int j = 0; j < 2; j++) {
      int col = n0 + wc * 64 + j * 32 + l31;
      float bv = bias ? bias[col] : 0.f;
#pragma unroll
      for (int r = 0; r < 16; r++) {
        int row = r0 + wr * 64 + i * 32 + (r & 3) + 8 * (r >> 2) + 4 * lhi;
        if (row < M) {
          float v = acc[i][j][r] + bv;
          if (act == 1) v = leaky(v);
          else if (act == 2) v = elu1(v);
          else if (act == 3) v = fmaxf(v, 0.f);
          if (Cf) Cf[(size_t)row * Nn + col] = v;
          if (Ch) Ch[pf_idx(row, col)] = (f16)v;  // only used when Nn==HID
        }
      }
    }
}

// ------------- MFMA f16 GEMM + fused row-dot epilogue (separate instantiation) -------------
__global__ __launch_bounds__(256) void k_hgemm_dot(
    const f16* __restrict__ Apf, const f16* __restrict__ Bpf,
    float* __restrict__ Cf, f16* __restrict__ Ch, int M,
    const float* __restrict__ dv1, const float* __restrict__ dv2,
    float* __restrict__ od1, float* __restrict__ od2)
{
  const int nct = HID >> 7;  // 3
  const int id = blockIdx.x;
  const int lane8 = id & 7, chunk = id >> 3;
  const int ct = chunk % nct, rg = chunk / nct;
  const int rt = rg * 8 + lane8;
  const int Mt = (M + 127) >> 7;
  if (rt >= Mt) return;
  const int r0 = rt * 128, n0 = ct * 128;
  const int tid = threadIdx.x;
  const int wid = tid >> 6, lane = tid & 63;
  const int wr = wid >> 1, wc = wid & 1;
  const int l31 = lane & 31, lhi = lane >> 5;
  const size_t lane_off = (size_t)(lhi * 32 + l31) * 8;
  const f16* pA[2]; const f16* pB[2];
#pragma unroll
  for (int i = 0; i < 2; i++) {
    pA[i] = Apf + (size_t)(r0 / 32 + wr * 2 + i) * PF_RB_STRIDE + lane_off;
    pB[i] = Bpf + (size_t)(n0 / 32 + wc * 2 + i) * PF_RB_STRIDE + lane_off;
  }
  f32x16 acc[2][2];
#pragma unroll
  for (int i = 0; i < 2; i++)
#pragma unroll
    for (int j = 0; j < 2; j++)
#pragma unroll
      for (int r = 0; r < 16; r++) acc[i][j][r] = 0.f;
  f16x8 af[2], bf[2], naf[2], nbf[2];
#pragma unroll
  for (int i = 0; i < 2; i++) { af[i] = *(const f16x8*)(pA[i]); bf[i] = *(const f16x8*)(pB[i]); }
#pragma unroll 4
  for (int ks = 0; ks < 24; ks++) {
    const size_t noff = (size_t)(ks < 23 ? ks + 1 : 23) * PF_KS_STRIDE;
#pragma unroll
    for (int i = 0; i < 2; i++) { naf[i] = *(const f16x8*)(pA[i] + noff); nbf[i] = *(const f16x8*)(pB[i] + noff); }
#pragma unroll
    for (int i = 0; i < 2; i++)
#pragma unroll
      for (int j = 0; j < 2; j++)
        acc[i][j] = __builtin_amdgcn_mfma_f32_32x32x16_f16(af[i], bf[j], acc[i][j], 0, 0, 0);
#pragma unroll
    for (int i = 0; i < 2; i++) { af[i] = naf[i]; bf[i] = nbf[i]; }
  }
#pragma unroll
  for (int i = 0; i < 2; i++)
#pragma unroll
    for (int j = 0; j < 2; j++) {
      int col = n0 + wc * 64 + j * 32 + l31;
#pragma unroll
      for (int r = 0; r < 16; r++) {
        int row = r0 + wr * 64 + i * 32 + (r & 3) + 8 * (r >> 2) + 4 * lhi;
        if (row < M) {
          float v = acc[i][j][r];
          Cf[(size_t)row * HID + col] = v;
          if (Ch) Ch[pf_idx(row, col)] = (f16)v;
        }
      }
    }
  // fused row-dot epilogue on raw accumulators
  const float w1a = dv1[n0 + wc * 64 + l31];
  const float w1b = dv1[n0 + wc * 64 + 32 + l31];
  const float w2a = dv2 ? dv2[n0 + wc * 64 + l31] : 0.f;
  const float w2b = dv2 ? dv2[n0 + wc * 64 + 32 + l31] : 0.f;
#pragma unroll
  for (int i = 0; i < 2; i++)
#pragma unroll
    for (int r = 0; r < 16; r++) {
      int row = r0 + wr * 64 + i * 32 + (r & 3) + 8 * (r >> 2) + 4 * lhi;
      float p1 = acc[i][0][r] * w1a + acc[i][1][r] * w1b;
      float p2 = acc[i][0][r] * w2a + acc[i][1][r] * w2b;
#pragma unroll
      for (int o = 16; o; o >>= 1) {
        p1 += __shfl_xor(p1, o, 64);
        p2 += __shfl_xor(p2, o, 64);
      }
      if (l31 == 0 && row < M) {
        atomicAdd(&od1[row], p1);
        if (od2) atomicAdd(&od2[row], p2);
      }
    }
}

// ------------- MFMA f16 fused GRU v5 (proven optimum): 4 accs, 2-deep A / 1-deep W -------------
__global__ __launch_bounds__(256) void k_gru_hgemm(
    const f16* __restrict__ Upf, const f16* __restrict__ Hpf,
    const f16* __restrict__ Wip, const f16* __restrict__ Whp,
    const float* __restrict__ bi, const float* __restrict__ bh,
    float* __restrict__ Xo, f16* __restrict__ Xoh, int M)
{
  const int id = blockIdx.x;
  const int lane8 = id & 7, chunk = id >> 3;
  const int ct = chunk % 6, rg = chunk / 6;
  const int rt = rg * 8 + lane8;
  const int Mt = (M + 63) >> 6;
  if (rt >= Mt) return;
  const int r0 = rt * 64, c0 = ct * 64;
  const int tid = threadIdx.x;
  const int wid = tid >> 6, lane = tid & 63;
  const int wr = wid >> 1, wc = wid & 1;
  const int l31 = lane & 31, lhi = lane >> 5;
  const size_t lane_off = (size_t)(lhi * 32 + l31) * 8;
  const f16* pU  = Upf + (size_t)(r0 / 32 + wr) * PF_RB_STRIDE + lane_off;
  const f16* pH  = Hpf + (size_t)(r0 / 32 + wr) * PF_RB_STRIDE + lane_off;
  const f16* pWi = Wip + (size_t)(c0 / 32 + wc) * PF_RB_STRIDE + lane_off;
  const f16* pWh = Whp + (size_t)(c0 / 32 + wc) * PF_RB_STRIDE + lane_off;
#define Z16 {0,0,0,0,0,0,0,0,0,0,0,0,0,0,0,0}
  f32x16 accR = Z16, accZ = Z16, aN = Z16, hN = Z16;
  f16x8 au0, ah0, au1, ah1, bir, biz, bin, bhr, bhz, bhn;
  au0 = *(const f16x8*)(pU);
  ah0 = *(const f16x8*)(pH);
  au1 = *(const f16x8*)(pU + PF_KS_STRIDE);
  ah1 = *(const f16x8*)(pH + PF_KS_STRIDE);
  bir = *(const f16x8*)(pWi);
  biz = *(const f16x8*)(pWi + PF_GATE_STRIDE);
  bin = *(const f16x8*)(pWi + 2 * PF_GATE_STRIDE);
  bhr = *(const f16x8*)(pWh);
  bhz = *(const f16x8*)(pWh + PF_GATE_STRIDE);
  bhn = *(const f16x8*)(pWh + 2 * PF_GATE_STRIDE);
#pragma unroll 4
  for (int ks = 0; ks < 24; ks++) {
    const size_t woff = (size_t)(ks < 23 ? ks + 1 : 23) * PF_KS_STRIDE;
    const size_t aoff = (size_t)(ks < 22 ? ks + 2 : 23) * PF_KS_STRIDE;
    f16x8 nau  = *(const f16x8*)(pU + aoff);
    f16x8 nah  = *(const f16x8*)(pH + aoff);
    f16x8 nbir = *(const f16x8*)(pWi + woff);
    f16x8 nbiz = *(const f16x8*)(pWi + PF_GATE_STRIDE + woff);
    f16x8 nbin = *(const f16x8*)(pWi + 2 * PF_GATE_STRIDE + woff);
    f16x8 nbhr = *(const f16x8*)(pWh + woff);
    f16x8 nbhz = *(const f16x8*)(pWh + PF_GATE_STRIDE + woff);
    f16x8 nbhn = *(const f16x8*)(pWh + 2 * PF_GATE_STRIDE + woff);
    accR = __builtin_amdgcn_mfma_f32_32x32x16_f16(au0, bir, accR, 0, 0, 0);
    accR = __builtin_amdgcn_mfma_f32_32x32x16_f16(ah0, bhr, accR, 0, 0, 0);
    accZ = __builtin_amdgcn_mfma_f32_32x32x16_f16(au0, biz, accZ, 0, 0, 0);
    accZ = __builtin_amdgcn_mfma_f32_32x32x16_f16(ah0, bhz, accZ, 0, 0, 0);
    aN   = __builtin_amdgcn_mfma_f32_32x32x16_f16(au0, bin, aN, 0, 0, 0);
    hN   = __builtin_amdgcn_mfma_f32_32x32x16_f16(ah0, bhn, hN, 0, 0, 0);
    au0 = au1; ah0 = ah1; au1 = nau; ah1 = nah;
    bir = nbir; biz = nbiz; bin = nbin;
    bhr = nbhr; bhz = nbhz; bhn = nbhn;
  }
  const int col = c0 + wc * 32 + l31;  // in [0, 384)
  const float brz = bi[col] + bh[col];
  const float bzz = bi[HID + col] + bh[HID + col];
  const float bin_ = bi[2 * HID + col];
  const float bhn_ = bh[2 * HID + col];
#pragma unroll
  for (int r = 0; r < 16; r++) {
    int row = r0 + wr * 32 + (r & 3) + 8 * (r >> 2) + 4 * lhi;
    if (row < M) {
      float rg_ = sigm(accR[r] + brz);
      float zg  = sigm(accZ[r] + bzz);
      float ng  = tanhf(aN[r] + bin_ + rg_ * (hN[r] + bhn_));
      float hp  = (float)Hpf[pf_idx(row, col)];
      float o = (1.f - zg) * ng + zg * hp;
      o = fmaxf(o, 0.f);
      if (Xo) Xo[(size_t)row * HID + col] = o;
      Xoh[pf_idx(row, col)] = (f16)o;
    }
  }
}

// ---- single fused weight pack: all 11 weights -> PF f16 in one launch ----
__global__ void k_wpack_all(
    const float* __restrict__ w0, const float* __restrict__ w1,
    const float* __restrict__ w2, const float* __restrict__ w3,
    const float* __restrict__ w4, const float* __restrict__ w5,
    const float* __restrict__ w6, const float* __restrict__ w7,
    const float* __restrict__ w8, const float* __restrict__ w9,
    const float* __restrict__ w10,
    f16* __restrict__ d0, f16* __restrict__ d1, f16* __restrict__ d2,
    f16* __restrict__ d3, f16* __restrict__ d4, f16* __restrict__ d5,
    f16* __restrict__ d6, f16* __restrict__ d7, f16* __restrict__ d8,
    f16* __restrict__ d9, f16* __restrict__ d10)
{
  long t = (long)blockIdx.x * blockDim.x + threadIdx.x;
  if (t >= 3538944L) return;
  const float* W; f16* Wp; int Nn; long tt;
  if (t < 589824L) {
    int s = (int)(t / 147456L); tt = t - (long)s * 147456L; Nn = HID;
    if (s == 0) { W = w0; Wp = d0; } else if (s == 1) { W = w1; Wp = d1; }
    else if (s == 2) { W = w2; Wp = d2; } else { W = w3; Wp = d3; }
  } else if (t < 3244032L) {
    long u = t - 589824L;
    int s = (int)(u / 442368L); tt = u - (long)s * 442368L; Nn = 3 * HID;
    if (s == 0) { W = w4; Wp = d4; } else if (s == 1) { W = w5; Wp = d5; }
    else if (s == 2) { W = w6; Wp = d6; } else if (s == 3) { W = w7; Wp = d7; }
    else if (s == 4) { W = w8; Wp = d8; } else { W = w9; Wp = d9; }
  } else {
    tt = t - 3244032L; Nn = OUTD; W = w10; Wp = d10;
  }
  int elem = (int)(tt & 7); long c = tt >> 3;
  int l31 = (int)(c & 31); long q = c >> 5;
  int lhi = (int)(q & 1); long p = q >> 1;
  int ks = (int)(p % 24); int rb = (int)(p / 24);
  int n = rb * 32 + l31, k = ks * 16 + lhi * 8 + elem;
  Wp[tt] = (f16)W[(size_t)k * Nn + n];
}

// node embed v2: one wave per row. Writes PF f16 only; fuses xr = x1 @ att_r.
__global__ void k_node_embed2(const int* __restrict__ xi, const float* __restrict__ T1,
                              const float* __restrict__ b, const float* __restrict__ att_r,
                              f16* __restrict__ x1h, float* __restrict__ xr, int n)
{
  int w = (int)(((long)blockIdx.x * blockDim.x + threadIdx.x) >> 6);
  int lane = threadIdx.x & 63;
  if (w >= n) return;
  int idx[9];
#pragma unroll
  for (int j = 0; j < 9; j++) idx[j] = xi[w * 9 + j];
  float s = 0.f;
#pragma unroll
  for (int t = 0; t < 6; t++) {
    int c = lane + 64 * t;
    float v = b[c];
#pragma unroll
    for (int j = 0; j < 9; j++) v += T1[(size_t)idx[j] * HID + c];
    v = leaky(v);
    x1h[pf_idx(w, c)] = (f16)v;
    s += v * att_r[c];
  }
  for (int o = 32; o; o >>= 1) s += __shfl_down(s, o, 64);
  if (lane == 0) xr[w] = s;
}

// one 64-lane wave per row: out[r] = dot(X[r,:], v)
__global__ void k_rowdot(const float* __restrict__ X, const float* __restrict__ v,
                         float* __restrict__ out, int M)
{
  int w = (int)(((long)blockIdx.x * blockDim.x + threadIdx.x) >> 6);
  int lane = threadIdx.x & 63;
  if (w >= M) return;
  float s = 0.f;
  for (int j = lane; j < HID; j += 64) s += X[(size_t)w * HID + j] * v[j];
  for (int o = 32; o; o >>= 1) s += __shfl_down(s, o, 64);
  if (lane == 0) out[w] = s;
}

// fused init: cnt=0, sS/sD/a_node=0, gstart via binary search (batch sorted)
__global__ void k_init(const int* __restrict__ batch, int* __restrict__ cnt,
                       float* __restrict__ sz, int* __restrict__ gstart, int n, int G)
{
  int i = (int)((long)blockIdx.x * blockDim.x + threadIdx.x);
  if (i < n) {
    cnt[i] = 0;
    sz[i] = 0.f; sz[n + i] = 0.f; sz[2 * n + i] = 0.f;  // sS, sD, a_node
  }
  if (i <= G) {
    int lo = 0, hi = n;
    while (lo < hi) { int mid = (lo + hi) >> 1; if (batch[mid] < i) lo = mid + 1; else hi = mid; }
    gstart[i] = lo;
  }
}

// ---- CSR build over dst: degree count -> single-block scan -> fill ----
__global__ void k_deg(const int* __restrict__ dst, int* __restrict__ cnt, int ne)
{
  int e = (int)((long)blockIdx.x * blockDim.x + threadIdx.x);
  if (e >= ne) return;
  atomicAdd(&cnt[dst[e]], 1);
}

__global__ __launch_bounds__(1024) void k_scan(const int* __restrict__ cnt,
                                               int* __restrict__ rowptr,
                                               int* __restrict__ cursor)
{
  __shared__ int part[1024];
  const int tid = threadIdx.x;
  const int c0 = tid * 30, c1 = min(c0 + 30, NN);
  int s = 0;
  for (int i = c0; i < c1; i++) s += cnt[i];
  part[tid] = s;
  __syncthreads();
  for (int o = 1; o < 1024; o <<= 1) {
    int v = (tid >= o) ? part[tid - o] : 0;
    __syncthreads();
    part[tid] += v;
    __syncthreads();
  }
  int run = (tid ? part[tid - 1] : 0);
  for (int i = c0; i < c1; i++) { rowptr[i] = run; cursor[i] = run; run += cnt[i]; }
  if (tid == 1023) rowptr[NN] = part[1023];
}

__global__ void k_fill(const int* __restrict__ dst, int* __restrict__ cursor,
                       int* __restrict__ elist, int ne)
{
  int e = (int)((long)blockIdx.x * blockDim.x + threadIdx.x);
  if (e >= ne) return;
  int p = atomicAdd(&cursor[dst[e]], 1);
  elist[p] = e;
}

// ---- GATEConv fused aggregation: one wave per node, online softmax, PF out ----
__global__ void k_gate_agg(const float* __restrict__ P, const float* __restrict__ Te,
                           const int* __restrict__ ei, const int* __restrict__ eai,
                           const float* __restrict__ attl, const float* __restrict__ xr,
                           const int* __restrict__ rowptr, const int* __restrict__ elist,
                           f16* __restrict__ Hout, int n)
{
  int node = (int)(((long)blockIdx.x * blockDim.x + threadIdx.x) >> 6);
  int lane = threadIdx.x & 63;
  if (node >= n) return;
  const int e0 = rowptr[node], e1 = rowptr[node + 1];
  const float xrd = xr[node];
  float h0 = 0.f, h1 = 0.f, h2 = 0.f, h3 = 0.f, h4 = 0.f, h5 = 0.f;
  float mx = -3.4e38f, s = 0.f;
  for (int q = e0; q < e1; q++) {
    int e = elist[q];
    int src = ei[e];
    int i0 = eai[e * 3], i1 = eai[e * 3 + 1], i2 = eai[e * 3 + 2];
    float m[6];
    float dot = 0.f;
#pragma unroll
    for (int t = 0; t < 6; t++) {
      int c = lane + 64 * t;
      float v = P[(size_t)src * HID + c] + Te[(size_t)i0 * HID + c]
              + Te[(size_t)i1 * HID + c] + Te[(size_t)i2 * HID + c];
      v = leaky(v);
      m[t] = v;
      dot += v * attl[c];
    }
#pragma unroll
    for (int o = 32; o; o >>= 1) dot += __shfl_xor(dot, o, 64);
    float a = leaky(dot + xrd);
    if (a > mx) {
      float f = expf(mx - a);   // first edge: exp(-huge)=0
      s *= f; h0 *= f; h1 *= f; h2 *= f; h3 *= f; h4 *= f; h5 *= f;
      mx = a;
    }
    float w = expf(a - mx);
    s += w;
    h0 += w * m[0]; h1 += w * m[1]; h2 += w * m[2];
    h3 += w * m[3]; h4 += w * m[4]; h5 += w * m[5];
  }
  const float inv = 1.f / (s + 1e-16f);
  Hout[pf_idx(node, lane)]           = (f16)(h0 * inv);
  Hout[pf_idx(node, lane + 64)]      = (f16)(h1 * inv);
  Hout[pf_idx(node, lane + 128)]     = (f16)(h2 * inv);
  Hout[pf_idx(node, lane + 192)]     = (f16)(h3 * inv);
  Hout[pf_idx(node, lane + 256)]     = (f16)(h4 * inv);
  Hout[pf_idx(node, lane + 320)]     = (f16)(h5 * inv);
}

// ---- GAT fused aggregation: one wave per node, online softmax, +bias +elu, PF out ----
__global__ void k_gat_agg(const float* __restrict__ XL, const int* __restrict__ ei,
                          const float* __restrict__ sS, const float* __restrict__ sD,
                          const float* __restrict__ gat_b,
                          const int* __restrict__ rowptr, const int* __restrict__ elist,
                          f16* __restrict__ Hout, int n)
{
  int node = (int)(((long)blockIdx.x * blockDim.x + threadIdx.x) >> 6);
  int lane = threadIdx.x & 63;
  if (node >= n) return;
  const int e0 = rowptr[node], e1 = rowptr[node + 1];
  const float sDn = sD[node];
  float h0 = 0.f, h1 = 0.f, h2 = 0.f, h3 = 0.f, h4 = 0.f, h5 = 0.f;
  float mx = -3.4e38f, s = 0.f;
  for (int q = e0; q < e1; q++) {
    int e = elist[q];
    int src = ei[e];
    float a = leaky(sS[src] + sDn);
    if (a > mx) {
      float f = expf(mx - a);
      s *= f; h0 *= f; h1 *= f; h2 *= f; h3 *= f; h4 *= f; h5 *= f;
      mx = a;
    }
    float w = expf(a - mx);
    s += w;
    const float* row = XL + (size_t)src * HID;
    h0 += w * row[lane];
    h1 += w * row[lane + 64];
    h2 += w * row[lane + 128];
    h3 += w * row[lane + 192];
    h4 += w * row[lane + 256];
    h5 += w * row[lane + 320];
  }
  const float inv = 1.f / (s + 1e-16f);
  Hout[pf_idx(node, lane)]       = (f16)elu1(h0 * inv + gat_b[lane]);
  Hout[pf_idx(node, lane + 64)]  = (f16)elu1(h1 * inv + gat_b[lane + 64]);
  Hout[pf_idx(node, lane + 128)] = (f16)elu1(h2 * inv + gat_b[lane + 128]);
  Hout[pf_idx(node, lane + 192)] = (f16)elu1(h3 * inv + gat_b[lane + 192]);
  Hout[pf_idx(node, lane + 256)] = (f16)elu1(h4 * inv + gat_b[lane + 256]);
  Hout[pf_idx(node, lane + 320)] = (f16)elu1(h5 * inv + gat_b[lane + 320]);
}

// per-graph sum (sorted batch) from PF f16 x3: OUTa = relu(sum x3), dual f32 + PF
__global__ __launch_bounds__(384) void k_graph_sum_pf(const f16* __restrict__ Xpf,
                                                      const int* __restrict__ gstart,
                                                      float* __restrict__ OUTa,
                                                      f16* __restrict__ OUTaPF)
{
  const int g = blockIdx.x;
  const int tid = threadIdx.x;
  const int s0 = gstart[g], s1 = gstart[g + 1];
  float acc = 0.f;
  for (int i = s0; i < s1; i++) acc += (float)Xpf[pf_idx(i, tid)];
  acc = fmaxf(acc, 0.f);
  OUTa[(size_t)g * HID + tid] = acc;
  OUTaPF[pf_idx(g, tid)] = (f16)acc;
}

// fused per-graph readout iteration: a_g dot + segment softmax + weighted sum + elu -> HM PF
__global__ __launch_bounds__(384) void k_mol_iter(
    const float* __restrict__ cur, const float* __restrict__ XLm,
    const float* __restrict__ a_node, const float* __restrict__ w_g,
    const float* __restrict__ mol_b, const int* __restrict__ gstart,
    f16* __restrict__ HMp)
{
  const int g = blockIdx.x;
  const int tid = threadIdx.x;
  const int lane = tid & 63, wv = tid >> 6;  // 6 waves
  __shared__ float red[6];
  __shared__ float wbuf[384];
  __shared__ float sh[3];
  const int s0 = gstart[g], s1 = gstart[g + 1];
  float p = cur[(size_t)g * HID + tid] * w_g[tid];
  for (int o = 32; o; o >>= 1) p += __shfl_down(p, o, 64);
  if (lane == 0) red[wv] = p;
  __syncthreads();
  if (tid == 0) { float s = 0.f; for (int i = 0; i < 6; i++) s += red[i]; sh[0] = s; }
  __syncthreads();
  const float ag = sh[0];
  float mx = -3.4e38f;
  for (int n = s0 + tid; n < s1; n += 384) mx = fmaxf(mx, leaky(a_node[n] + ag));
  for (int o = 32; o; o >>= 1) mx = fmaxf(mx, __shfl_down(mx, o, 64));
  __syncthreads();
  if (lane == 0) red[wv] = mx;
  __syncthreads();
  if (tid == 0) { float m = red[0]; for (int i = 1; i < 6; i++) m = fmaxf(m, red[i]); sh[1] = m; }
  __syncthreads();
  const float gmx = sh[1];
  float sm = 0.f;
  for (int n = s0 + tid; n < s1; n += 384) sm += expf(leaky(a_node[n] + ag) - gmx);
  for (int o = 32; o; o >>= 1) sm += __shfl_down(sm, o, 64);
  __syncthreads();
  if (lane == 0) red[wv] = sm;
  __syncthreads();
  if (tid == 0) { float s = 0.f; for (int i = 0; i < 6; i++) s += red[i]; sh[2] = s; }
  __syncthreads();
  const float inv = 1.f / (sh[2] + 1e-16f);
  float h = 0.f;
  for (int base = s0; base < s1; base += 384) {
    int cnt = min(384, s1 - base);
    __syncthreads();
    if (tid < cnt) wbuf[tid] = expf(leaky(a_node[base + tid] + ag) - gmx) * inv;
    __syncthreads();
    for (int k = 0; k < cnt; k++) h += XLm[(size_t)(base + k) * HID + tid] * wbuf[k];
  }
  h = elu1(h + mol_b[tid]);
  HMp[pf_idx(g, tid)] = (f16)h;
}

extern "C" void kernel_launch(void* const* d_in, const int* in_sizes, int n_in,
                              void* d_out, int out_size, void* d_ws, size_t ws_size,
                              hipStream_t stream)
{
  const int* x_idx = (const int*)d_in[0];
  const int* edge_index = (const int*)d_in[1];
  const int* eai = (const int*)d_in[2];
  const int* batch = (const int*)d_in[3];
  const float* x_emb = (const float*)d_in[4];
  const float* e_emb = (const float*)d_in[5];
  const float* lin1_W = (const float*)d_in[6];
  const float* lin1_b = (const float*)d_in[7];
  const float* att_l = (const float*)d_in[8];
  const float* att_r = (const float*)d_in[9];
  const float* gl1_W = (const float*)d_in[10];
  const float* gl2_W = (const float*)d_in[11];
  const float* gate_b = (const float*)d_in[12];
  const float* gru1_Wi = (const float*)d_in[13];
  const float* gru1_Wh = (const float*)d_in[14];
  const float* gru1_bi = (const float*)d_in[15];
  const float* gru1_bh = (const float*)d_in[16];
  const float* gat_W = (const float*)d_in[17];
  const float* gat_as = (const float*)d_in[18];
  const float* gat_ad = (const float*)d_in[19];
  const float* gat_b = (const float*)d_in[20];
  const float* gru2_Wi = (const float*)d_in[21];
  const float* gru2_Wh = (const float*)d_in[22];
  const float* gru2_bi = (const float*)d_in[23];
  const float* gru2_bh = (const float*)d_in[24];
  const float* mol_W = (const float*)d_in[25];
  const float* mol_as = (const float*)d_in[26];
  const float* mol_ad = (const float*)d_in[27];
  const float* mol_b = (const float*)d_in[28];
  const float* mgru_Wi = (const float*)d_in[29];
  const float* mgru_Wh = (const float*)d_in[30];
  const float* mgru_bi = (const float*)d_in[31];
  const float* mgru_bh = (const float*)d_in[32];
  const float* lin2_W = (const float*)d_in[33];
  const float* lin2_b = (const float*)d_in[34];
  float* outp = (float*)d_out;

  const size_t NB = (size_t)NN * HID;
  const size_t GB = (size_t)NG * HID;
  const size_t PFH = (size_t)940 * PF_RB_STRIDE;  // f16 elems (pad rows to 30080)
  const size_t PFG = (size_t)40 * PF_RB_STRIDE;

  float* ws = (float*)d_ws;
  size_t off = 0;
  auto alloc = [&](size_t n) { float* p = ws + off; off += n; return p; };
  auto alloch = [&](size_t n) { f16* p = (f16*)(ws + off); off += (n + 1) / 2; return p; };
  float* A    = alloc(NB);
  float* B    = alloc(NB);
  f16* H1 = alloch(PFH);
  f16* H2 = alloch(PFH);
  f16* H3 = alloch(PFH);
  f16* W1p   = alloch((size_t)HID * HID);
  f16* W2p   = alloch((size_t)HID * HID);
  f16* Wgatp = alloch((size_t)HID * HID);
  f16* Wmolp = alloch((size_t)HID * HID);
  f16* Wg1ip = alloch((size_t)3 * HID * HID);
  f16* Wg1hp = alloch((size_t)3 * HID * HID);
  f16* Wg2ip = alloch((size_t)3 * HID * HID);
  f16* Wg2hp = alloch((size_t)3 * HID * HID);
  f16* Wmgip = alloch((size_t)3 * HID * HID);
  f16* Wmghp = alloch((size_t)3 * HID * HID);
  f16* Wl2p  = alloch((size_t)HID * OUTD);
  f16* OUTaPF = alloch(PFG);
  f16* OUTbPF = alloch(PFG);
  f16* HMp    = alloch(PFG);
  float* T1   = alloc((size_t)178 * HID);
  float* Te   = alloc((size_t)18 * HID);
  float* w_g  = alloc(HID);
  float* xr   = alloc(NN);
  float* sS   = alloc(NN);   // sS, sD, a_node contiguous (zeroed by k_init)
  float* sD   = alloc(NN);
  float* a_node = alloc(NN);
  float* OUTa = alloc(GB);
  float* OUTb = alloc(GB);
  int* gstart = (int*)alloc(NG + 2);
  int* cnt    = (int*)alloc(NN);
  int* rowptr = (int*)alloc(NN + 2);
  int* cursor = (int*)alloc(NN);
  int* elist  = (int*)alloc(NE);
  (void)n_in; (void)in_sizes; (void)out_size;
  if (ws_size < off * sizeof(float)) return;  // fail loud, not with a GPU fault

  const int* dstArr = edge_index + NE;
  dim3 blk(256);
  auto g1 = [](long n) { return dim3((unsigned)((n + 255) / 256)); };
  auto gw = [](long waves) { return dim3((unsigned)((waves * 64 + 255) / 256)); };
  const int MtH = (NN + 127) / 128;                       // 235
  const dim3 gH((unsigned)(8 * 3 * ((MtH + 7) / 8)));     // 720
  const int MtR = (NN + 63) / 64;                         // 469
  const dim3 gR((unsigned)(8 * 6 * ((MtR + 7) / 8)));     // 2832
  const int MtGH = (NG + 127) / 128;                      // 10
  const dim3 gF((unsigned)(8 * 6 * ((MtGH + 7) / 8)));    // 96   (Nn=OUTD)
  const int MtGR = (NG + 63) / 64;                        // 19
  const dim3 gRG((unsigned)(8 * 6 * ((MtGR + 7) / 8)));   // 144
  const float* FN = nullptr;
  float* FNm = nullptr;

  // ---- weight prep (one launch) + tables + fused init + CSR ----
  hipLaunchKernelGGL(k_wpack_all, g1(3538944L), blk, 0, stream,
                     gl1_W, gl2_W, gat_W, mol_W,
                     gru1_Wi, gru1_Wh, gru2_Wi, gru2_Wh, mgru_Wi, mgru_Wh, lin2_W,
                     W1p, W2p, Wgatp, Wmolp,
                     Wg1ip, Wg1hp, Wg2ip, Wg2hp, Wmgip, Wmghp, Wl2p);
  hipLaunchKernelGGL(k_gemm, dim3(HID / 64, 3), blk, 0, stream,
                     x_emb, lin1_W, nullptr, T1, 178, HID, EMB, 0);
  hipLaunchKernelGGL(k_gemm, dim3(HID / 64, 1), blk, 0, stream,
                     e_emb, gl1_W + (size_t)HID * HID, nullptr, Te, 18, HID, EMB, 0);
  hipLaunchKernelGGL(k_rowdot, gw(HID), blk, 0, stream, mol_W, mol_ad, w_g, HID);
  hipLaunchKernelGGL(k_init, g1(NN), blk, 0, stream, batch, cnt, sS, gstart, NN, NG);
  hipLaunchKernelGGL(k_deg, g1(NE), blk, 0, stream, dstArr, cnt, NE);
  hipLaunchKernelGGL(k_scan, dim3(1), dim3(1024), 0, stream, cnt, rowptr, cursor);
  hipLaunchKernelGGL(k_fill, g1(NE), blk, 0, stream, dstArr, cursor, elist, NE);

  // ---- x1 (PF) + fused xr ----
  hipLaunchKernelGGL(k_node_embed2, gw(NN), blk, 0, stream, x_idx, T1, lin1_b, att_r, H1, xr, NN);

  // ---- GATEConv ----
  hipLaunchKernelGGL(k_hgemm, gH, blk, 0, stream, H1, W1p, FN, B, (f16*)nullptr, NN, HID, 0); // P
  hipLaunchKernelGGL(k_gate_agg, gw(NN), blk, 0, stream, B, Te, edge_index, eai, att_l, xr,
                     rowptr, elist, H2, NN);
  hipLaunchKernelGGL(k_hgemm, gH, blk, 0, stream, H2, W2p, gate_b, (float*)nullptr, H3, NN, HID, 2); // elu(h)
  hipLaunchKernelGGL(k_gru_hgemm, gR, blk, 0, stream, H3, H1, Wg1ip, Wg1hp,
                     gru1_bi, gru1_bh, (float*)nullptr, H2, NN);            // x2 -> H2

  // ---- GAT layer ----
  hipLaunchKernelGGL(k_hgemm_dot, gH, blk, 0, stream, H2, Wgatp, B, (f16*)nullptr, NN,
                     gat_as, gat_ad, sS, sD);                               // XL + fused sS/sD
  hipLaunchKernelGGL(k_gat_agg, gw(NN), blk, 0, stream, B, edge_index, sS, sD, gat_b,
                     rowptr, elist, H1, NN);                                // elu(h2+b) -> H1
  hipLaunchKernelGGL(k_gru_hgemm, gR, blk, 0, stream, H1, H2, Wg2ip, Wg2hp,
                     gru2_bi, gru2_bh, (float*)nullptr, H3, NN);            // x3 -> H3 PF only

  // ---- molecule readout ----
  hipLaunchKernelGGL(k_graph_sum_pf, dim3(NG), dim3(384), 0, stream, H3, gstart, OUTa, OUTaPF);
  hipLaunchKernelGGL(k_hgemm_dot, gH, blk, 0, stream, H3, Wmolp, A, (f16*)nullptr, NN,
                     mol_as, FN, a_node, FNm);                              // XLm + fused a_node

  float* cur = OUTa;   f16* curPF = OUTaPF;
  float* nxt = OUTb;   f16* nxtPF = OUTbPF;
  for (int t = 0; t < 3; t++) {
    hipLaunchKernelGGL(k_mol_iter, dim3(NG), dim3(384), 0, stream,
                       cur, A, a_node, w_g, mol_b, gstart, HMp);
    hipLaunchKernelGGL(k_gru_hgemm, gRG, blk, 0, stream, HMp, curPF, Wmgip, Wmghp,
                       mgru_bi, mgru_bh, nxt, nxtPF, NG);
    float* tf = cur; cur = nxt; nxt = tf;
    f16* th = curPF; curPF = nxtPF; nxtPF = th;
  }

  // ---- final projection: out = cur @ lin2_W + lin2_b ----
  hipLaunchKernelGGL(k_hgemm, gF, blk, 0, stream, curPF, Wl2p, lin2_b, outp, (f16*)nullptr,
                     NG, OUTD, 0);
}